// Round 9
// baseline (217.944 us; speedup 1.0000x reference)
//
#include <hip/hip_runtime.h>

// Problem constants (from reference)
#define NSTARS 2048
#define BATCH  256
#define PF     28
#define NGE    512
#define GF     32
#define OPD2   65536   // 256*256
#define KTOT   (PF + GF)  // 60
#define IJC    256     // ij elements per block
#define BG     32      // batches per accumulator group (2 groups/thread)

// ---------------------------------------------------------------------------
// Kernel 1: index search + W = [interm_poly | interm_graph] (k-major layout)
// Wt[k*BATCH + b], k in [0,60)
// ---------------------------------------------------------------------------
__global__ __launch_bounds__(256) void prep_kernel(
    const float* __restrict__ positions,  const float* __restrict__ obs_pos,
    const float* __restrict__ poly_dic,   const float* __restrict__ graph_dic,
    const float* __restrict__ alpha_poly, const float* __restrict__ alpha_graph,
    float* __restrict__ Wt)
{
    const int b = blockIdx.x;   // batch row
    const int t = threadIdx.x;  // 256 threads

    const float p0 = positions[2 * b];
    const float p1 = positions[2 * b + 1];

    // Faithful to argmax(eq.reshape(B,-1))//2 : first star n (row-major over
    // (n, coord)) where EITHER coordinate matches; all-false -> 0.
    int cand = 0x7fffffff;
    #pragma unroll
    for (int i = 0; i < NSTARS / 256; ++i) {
        const int n = t + i * 256;
        const float o0 = obs_pos[2 * n];
        const float o1 = obs_pos[2 * n + 1];
        if (o0 == p0 || o1 == p1) cand = min(cand, n);
    }
    __shared__ int smin[256];
    smin[t] = cand;
    __syncthreads();
    for (int s = 128; s > 0; s >>= 1) {
        if (t < s) smin[t] = min(smin[t], smin[t + s]);
        __syncthreads();
    }
    int idx = smin[0];
    if (idx == 0x7fffffff) idx = 0;  // argmax of all-False returns 0

    // interm_poly[j] = sum_p poly_dic[idx,p] * alpha_poly[p,j]
    if (t < PF) {
        float acc = 0.f;
        #pragma unroll
        for (int p = 0; p < PF; ++p)
            acc += poly_dic[idx * PF + p] * alpha_poly[p * PF + t];
        Wt[t * BATCH + b] = acc;
    }

    // interm_graph[g] = sum_e graph_dic[idx,e] * alpha_graph[e,g]
    // 8 partials of 64 elements each, reduced in LDS.
    __shared__ float psum[8][GF];
    {
        const int g = t & 31;
        const int r = t >> 5;
        float acc = 0.f;
        const int e0 = r * (NGE / 8);
        for (int e = e0; e < e0 + NGE / 8; ++e)
            acc += graph_dic[idx * NGE + e] * alpha_graph[e * GF + g];
        psum[r][g] = acc;
    }
    __syncthreads();
    if (t < GF) {
        float acc = 0.f;
        #pragma unroll
        for (int r = 0; r < 8; ++r) acc += psum[r][t];
        Wt[(PF + t) * BATCH + b] = acc;
    }
}

// ---------------------------------------------------------------------------
// Kernel 2: out[b, ij] = sum_k Wt[k, b] * S[k, ij]
//
// R0-R8 ledger: nine schedules (TM 8/16/32, LDS dbuf, counted vmcnt, occ
// 30->60%) all ~36-45 us because ALL replicated S 16-32x (251-503 MB) through
// the L2/L3 read path; R7's occ=60%/VALUBusy=33% showed the service path,
// not wave scheduling, is the invariant. This kernel ELIMINATES replication:
//
//  - block = (ij-chunk 256, batch-half 128); grid 512, 512 threads.
//    S chunk slds[60][256] = 61.4 KB staged ONCE via global_load_lds
//    (2 blocks/CU = 122.9 KB LDS, 16 waves/CU, all 256 CUs).
//    Global S reads: 251 MB -> 31 MB (2x compulsory). One barrier total.
//  - blocks id and id+256 share an S chunk and land on the same XCD
//    (256 % 8 == 0) -> the second stage is an L2 hit.
//  - thread: 1 ij x 64 batches = 2 reg-groups of 32 acc. Per k:
//    1 ds_read_b32 (stride 4B: 2 lanes/bank = conflict-free) +
//    2 s_load_dwordx16 (W, scalar pipe) + 32 v_fmac.
//    Pipe demand: VALU 12.8 us (floor, saturated), LDS ~4.6 us,
//    stores 67 MB ~10.6 us spread over per-group epilogues.
// ---------------------------------------------------------------------------
__global__ __launch_bounds__(512) void main_kernel(
    const float* __restrict__ S_poly, const float* __restrict__ S_graph,
    const float* __restrict__ Wt, float* __restrict__ out)
{
    __shared__ float slds[KTOT][IJC];   // 61440 B

    const int t    = threadIdx.x;       // 0..511
    const int id   = blockIdx.x;        // 0..511
    const int ijc  = id & 255;          // ij-chunk
    const int half = id >> 8;           // batch half: [half*128, half*128+128)
    const int ij0  = ijc * IJC;
    const int lane = t & 63;
    const int wv   = t >> 6;            // wave 0..7

    // ---- stage S chunk once: wave wv stages k-slices wv, wv+8, ... ----
    // Each global_load_lds: 64 lanes x 16 B = one full 1 KB k-slice.
    for (int kk = wv; kk < KTOT; kk += 8) {
        const float* base = (kk < PF)
            ? (S_poly  + (size_t)kk * OPD2)
            : (S_graph + (size_t)(kk - PF) * OPD2);
        __builtin_amdgcn_global_load_lds(
            (const __attribute__((address_space(1))) uint32_t*)(base + ij0 + lane * 4),
            (__attribute__((address_space(3))) uint32_t*)&slds[kk][0],
            16, 0, 0);
    }
    __syncthreads();   // full drain (vmcnt 0) + barrier -- once per kernel

    const int ijl   = t & 255;          // this thread's ij within the chunk
    const int layer = t >> 8;           // 0/1: which 64 batches of the half

    #pragma unroll
    for (int g = 0; g < 2; ++g) {
        const int b_base = half * 128 + layer * 64 + g * BG;
        const float* __restrict__ wk0 = Wt + b_base;   // uniform -> s_load

        float acc[BG];
        #pragma unroll
        for (int i = 0; i < BG; ++i) acc[i] = 0.f;

        #pragma unroll 4
        for (int k = 0; k < KTOT; ++k) {
            const float s = slds[k][ijl];              // ds_read_b32, 2/bank
            const float* wk = wk0 + k * BATCH;         // s_load_dwordx16 x2
            #pragma unroll
            for (int i = 0; i < BG; ++i)
                acc[i] = fmaf(wk[i], s, acc[i]);
        }

        #pragma unroll
        for (int i = 0; i < BG; ++i)
            __builtin_nontemporal_store(
                acc[i], out + (size_t)(b_base + i) * OPD2 + ij0 + ijl);
    }
}

// ---------------------------------------------------------------------------
extern "C" void kernel_launch(void* const* d_in, const int* in_sizes, int n_in,
                              void* d_out, int out_size, void* d_ws, size_t ws_size,
                              hipStream_t stream) {
    const float* positions   = (const float*)d_in[0];  // (256, 2)
    const float* obs_pos     = (const float*)d_in[1];  // (2048, 2)
    const float* poly_dic    = (const float*)d_in[2];  // (2048, 28)
    const float* graph_dic   = (const float*)d_in[3];  // (2048, 512)
    const float* alpha_poly  = (const float*)d_in[4];  // (28, 28)
    const float* alpha_graph = (const float*)d_in[5];  // (512, 32)
    const float* S_poly      = (const float*)d_in[6];  // (28, 256, 256)
    const float* S_graph     = (const float*)d_in[7];  // (32, 256, 256)
    float* out = (float*)d_out;                        // (256, 256, 256)

    float* Wt = (float*)d_ws;  // KTOT * BATCH floats = 60 KB

    prep_kernel<<<BATCH, 256, 0, stream>>>(positions, obs_pos, poly_dic,
                                           graph_dic, alpha_poly, alpha_graph,
                                           Wt);

    main_kernel<<<512, 512, 0, stream>>>(S_poly, S_graph, Wt, out);
}

// Round 10
// 135.805 us; speedup vs baseline: 1.6048x; 1.6048x over previous
//
#include <hip/hip_runtime.h>

// Problem constants (from reference)
#define NSTARS 2048
#define BATCH  256
#define PF     28
#define NGE    512
#define GF     32
#define OPD2   65536   // 256*256
#define KTOT   (PF + GF)  // 60
#define KC     15      // k-slices per LDS chunk
#define NCH    4       // 4 chunks of 15 = 60
#define BBLK   64      // batches per block
#define IJB    256     // ij per block

typedef float f32x4 __attribute__((ext_vector_type(4)));

// ---------------------------------------------------------------------------
// Kernel 1: index search + W = [interm_poly | interm_graph] (k-major layout)
// Wt[k*BATCH + b], k in [0,60)
// ---------------------------------------------------------------------------
__global__ __launch_bounds__(256) void prep_kernel(
    const float* __restrict__ positions,  const float* __restrict__ obs_pos,
    const float* __restrict__ poly_dic,   const float* __restrict__ graph_dic,
    const float* __restrict__ alpha_poly, const float* __restrict__ alpha_graph,
    float* __restrict__ Wt)
{
    const int b = blockIdx.x;   // batch row
    const int t = threadIdx.x;  // 256 threads

    const float p0 = positions[2 * b];
    const float p1 = positions[2 * b + 1];

    // Faithful to argmax(eq.reshape(B,-1))//2 : first star n (row-major over
    // (n, coord)) where EITHER coordinate matches; all-false -> 0.
    int cand = 0x7fffffff;
    #pragma unroll
    for (int i = 0; i < NSTARS / 256; ++i) {
        const int n = t + i * 256;
        const float o0 = obs_pos[2 * n];
        const float o1 = obs_pos[2 * n + 1];
        if (o0 == p0 || o1 == p1) cand = min(cand, n);
    }
    __shared__ int smin[256];
    smin[t] = cand;
    __syncthreads();
    for (int s = 128; s > 0; s >>= 1) {
        if (t < s) smin[t] = min(smin[t], smin[t + s]);
        __syncthreads();
    }
    int idx = smin[0];
    if (idx == 0x7fffffff) idx = 0;  // argmax of all-False returns 0

    // interm_poly[j] = sum_p poly_dic[idx,p] * alpha_poly[p,j]
    if (t < PF) {
        float acc = 0.f;
        #pragma unroll
        for (int p = 0; p < PF; ++p)
            acc += poly_dic[idx * PF + p] * alpha_poly[p * PF + t];
        Wt[t * BATCH + b] = acc;
    }

    // interm_graph[g] = sum_e graph_dic[idx,e] * alpha_graph[e,g]
    // 8 partials of 64 elements each, reduced in LDS.
    __shared__ float psum[8][GF];
    {
        const int g = t & 31;
        const int r = t >> 5;
        float acc = 0.f;
        const int e0 = r * (NGE / 8);
        for (int e = e0; e < e0 + NGE / 8; ++e)
            acc += graph_dic[idx * NGE + e] * alpha_graph[e * GF + g];
        psum[r][g] = acc;
    }
    __syncthreads();
    if (t < GF) {
        float acc = 0.f;
        #pragma unroll
        for (int r = 0; r < 8; ++r) acc += psum[r][t];
        Wt[(PF + t) * BATCH + b] = acc;
    }
}

// ---------------------------------------------------------------------------
// Kernel 2: out[b, ij] = sum_k Wt[k, b] * S[k, ij]
//
// R0-R9 ledger: the operand-supply triangle --
//   W per-k via s_load: OK only if K$-resident (<=4KB/block) -> forces S
//     replication 16-32x through L3 (R1-R8, all ~36-45 us);
//   W per-k via LDS broadcast at TM=16: LDS-pipe overload (R4);
//   W per-k via s_load at 30KB/block: K$ thrash + lgkm(0) drains (R9, 128us).
// This kernel takes the unvisited corner: BOTH operands in LDS, block sized
// so per-k LDS demand < FMA issue time:
//   - block = 256 ij x 64 batches; grid 1024 (256 ij-chunks x 4 y).
//     S replication 4x = 63 MB L3 (~5 us). The 4 sharers of an S chunk are
//     id, id+256, id+512, id+768 -> same XCD under %8 round-robin (free).
//   - thread = ij-quad (f32x4, quad=t&63) x 16 batches (group g=t>>6).
//     Per k per wave: 1 per-lane ds_read_b128 (S) + 4 broadcast ds_read_b128
//     (W, wave-uniform addr = free broadcast) ~= 60 cyc  vs  64 v_fmac =
//     128 cyc -> VALU-bound. All inner-loop operands in the ORDERED DS
//     domain -> counted lgkm waits pipeline cleanly (no SMEM mixing).
//   - S staged in 4 chunks of 15 k, double-buffered via global_load_lds
//     (wave-uniform dest, per-lane src); W staged once (15.4 KB).
//     Only 3 vmcnt(0)+barrier pairs in the whole kernel.
//   - LDS 46 KB -> 3 blocks/CU resident, 4 blocks/CU of work -> ragged
//     generations overlap the 66 MB store tail. Nontemporal stores.
// ---------------------------------------------------------------------------
__global__ __launch_bounds__(256) void main_kernel(
    const float* __restrict__ S_poly, const float* __restrict__ S_graph,
    const float* __restrict__ Wt, float* __restrict__ out)
{
    __shared__ float slds[2][KC][IJB];   // 30720 B
    __shared__ float wlds[KTOT][BBLK];   // 15360 B

    const int t    = threadIdx.x;        // 0..255
    const int id   = blockIdx.x;         // 0..1023
    const int ijc  = id & 255;           // ij-chunk
    const int y    = id >> 8;            // 0..3
    const int ij0  = ijc * IJB;
    const int b0   = y * BBLK;
    const int quad = t & 63;             // lane: ij-quad index
    const int g    = t >> 6;             // wave: batch group (16 b)

    // ---- W tile -> LDS once (60 x 64 floats), coalesced copy ----
    for (int i = t; i < KTOT * BBLK; i += 256)
        wlds[i >> 6][i & 63] = Wt[(i >> 6) * BATCH + b0 + (i & 63)];

    // ---- S chunk staging: wave g stages rows g, g+4, g+8, (g+12) ----
    // One global_load_lds per row: 64 lanes x 16B = the full 1KB row.
    auto stage = [&](int c, int d) {
        const int kbase = c * KC;
        for (int r = g; r < KC; r += 4) {
            const int k = kbase + r;
            const float* base = (k < PF)
                ? (S_poly  + (size_t)k * OPD2)
                : (S_graph + (size_t)(k - PF) * OPD2);
            __builtin_amdgcn_global_load_lds(
                (const __attribute__((address_space(1))) uint32_t*)(base + ij0 + quad * 4),
                (__attribute__((address_space(3))) uint32_t*)&slds[d][r][0],
                16, 0, 0);
        }
    };

    f32x4 acc[16];
    #pragma unroll
    for (int i = 0; i < 16; ++i) acc[i] = (f32x4)(0.f);

    stage(0, 0);
    asm volatile("s_waitcnt vmcnt(0)" ::: "memory");
    __syncthreads();   // W writes (lgkm) + chunk 0 (vmcnt) visible to all

    int buf = 0;
    #pragma unroll 1
    for (int c = 0; c < NCH; ++c) {
        if (c + 1 < NCH) stage(c + 1, buf ^ 1);

        const int kbase = c * KC;
        #pragma unroll 5
        for (int r = 0; r < KC; ++r) {
            const int k = kbase + r;
            const f32x4 sv = *reinterpret_cast<const f32x4*>(&slds[buf][r][quad * 4]);
            const f32x4 w0 = *reinterpret_cast<const f32x4*>(&wlds[k][g * 16 + 0]);
            const f32x4 w1 = *reinterpret_cast<const f32x4*>(&wlds[k][g * 16 + 4]);
            const f32x4 w2 = *reinterpret_cast<const f32x4*>(&wlds[k][g * 16 + 8]);
            const f32x4 w3 = *reinterpret_cast<const f32x4*>(&wlds[k][g * 16 + 12]);
            acc[0]  += w0.x * sv;  acc[1]  += w0.y * sv;
            acc[2]  += w0.z * sv;  acc[3]  += w0.w * sv;
            acc[4]  += w1.x * sv;  acc[5]  += w1.y * sv;
            acc[6]  += w1.z * sv;  acc[7]  += w1.w * sv;
            acc[8]  += w2.x * sv;  acc[9]  += w2.y * sv;
            acc[10] += w2.z * sv;  acc[11] += w2.w * sv;
            acc[12] += w3.x * sv;  acc[13] += w3.y * sv;
            acc[14] += w3.z * sv;  acc[15] += w3.w * sv;
        }

        if (c + 1 < NCH) {
            asm volatile("s_waitcnt vmcnt(0)" ::: "memory");  // chunk c+1 landed
            __syncthreads();   // all waves done reading buf; buf free for c+2
            buf ^= 1;
        }
    }

    // ---- epilogue: 16 coalesced f32x4 nt stores (1 KB per wave per b) ----
    #pragma unroll
    for (int i = 0; i < 16; ++i) {
        const int b = b0 + g * 16 + i;
        __builtin_nontemporal_store(
            acc[i],
            reinterpret_cast<f32x4*>(out + (size_t)b * OPD2 + ij0 + quad * 4));
    }
}

// ---------------------------------------------------------------------------
extern "C" void kernel_launch(void* const* d_in, const int* in_sizes, int n_in,
                              void* d_out, int out_size, void* d_ws, size_t ws_size,
                              hipStream_t stream) {
    const float* positions   = (const float*)d_in[0];  // (256, 2)
    const float* obs_pos     = (const float*)d_in[1];  // (2048, 2)
    const float* poly_dic    = (const float*)d_in[2];  // (2048, 28)
    const float* graph_dic   = (const float*)d_in[3];  // (2048, 512)
    const float* alpha_poly  = (const float*)d_in[4];  // (28, 28)
    const float* alpha_graph = (const float*)d_in[5];  // (512, 32)
    const float* S_poly      = (const float*)d_in[6];  // (28, 256, 256)
    const float* S_graph     = (const float*)d_in[7];  // (32, 256, 256)
    float* out = (float*)d_out;                        // (256, 256, 256)

    float* Wt = (float*)d_ws;  // KTOT * BATCH floats = 60 KB

    prep_kernel<<<BATCH, 256, 0, stream>>>(positions, obs_pos, poly_dic,
                                           graph_dic, alpha_poly, alpha_graph,
                                           Wt);

    main_kernel<<<1024, 256, 0, stream>>>(S_poly, S_graph, Wt, out);
}